// Round 1
// baseline (2865.813 us; speedup 1.0000x reference)
//
#include <hip/hip_runtime.h>
#include <hip/hip_bf16.h>

// Problem constants
#define BB 2
#define CC 256
#define HH 96
#define WW 96
#define HWP (HH*WW)        // 9216
#define DG 4
#define CG 64              // CC/DG
#define KK9 9

// d_out layout (return order): logits[2,1,96,96], bbox[2,4,96,96],
// shape_pred[2,2,96,96], loc[2,1,96,96]
#define OUT_LOGITS 0
#define OUT_BBOX   (2*1*HWP)                 // 18432
#define OUT_SHAPE  (OUT_BBOX + 2*4*HWP)      // 92160
#define OUT_LOC    (OUT_SHAPE + 2*2*HWP)     // 129024

// ---------------- Kernel 1: conv3x3 + bias + relu (fp32 direct) -------------
#define COT1 16
__global__ __launch_bounds__(256) void conv3x3_relu_kernel(
    const float* __restrict__ f, const float* __restrict__ w,
    const float* __restrict__ bias, float* __restrict__ t)
{
    const int tid = threadIdx.x;
    const int p   = blockIdx.x * 256 + tid;     // pixel
    const int co0 = blockIdx.y * COT1;          // output-channel base
    const int b   = blockIdx.z;
    const int y = p / WW, x = p % WW;

    __shared__ float wsm[COT1 * 32 * 9];        // 4608 floats = 18.4 KB

    float acc[COT1];
#pragma unroll
    for (int j = 0; j < COT1; j++) acc[j] = bias[co0 + j];

    const float* fb = f + (size_t)b * CC * HWP;

    for (int ci0 = 0; ci0 < CC; ci0 += 32) {
        __syncthreads();
        for (int idx = tid; idx < COT1 * 32 * 9; idx += 256) {
            int j  = idx / (32 * 9);
            int r  = idx % (32 * 9);
            int ci = r / 9;
            int k  = r % 9;
            wsm[idx] = w[((size_t)(co0 + j) * CC + (ci0 + ci)) * 9 + k];
        }
        __syncthreads();

        for (int ci = 0; ci < 32; ci++) {
            const float* fc = fb + (size_t)(ci0 + ci) * HWP;
            float v[9];
#pragma unroll
            for (int ky = 0; ky < 3; ky++) {
                const int yy = y + ky - 1;
                const bool vy = (yy >= 0) && (yy < HH);
#pragma unroll
                for (int kx = 0; kx < 3; kx++) {
                    const int xx = x + kx - 1;
                    const bool ok = vy && (xx >= 0) && (xx < WW);
                    v[ky * 3 + kx] = ok ? fc[yy * WW + xx] : 0.0f;
                }
            }
#pragma unroll
            for (int j = 0; j < COT1; j++) {
                const float* wj = &wsm[(j * 32 + ci) * 9];
                float a = acc[j];
#pragma unroll
                for (int k = 0; k < 9; k++) a = fmaf(v[k], wj[k], a);
                acc[j] = a;
            }
        }
    }

    float* tb = t + ((size_t)b * CC + co0) * HWP + p;
#pragma unroll
    for (int j = 0; j < COT1; j++) tb[(size_t)j * HWP] = fmaxf(acc[j], 0.0f);
}

// ------------- Kernel 2: loc / shape_pred heads + offset (fused) ------------
__global__ __launch_bounds__(64) void heads1_kernel(
    const float* __restrict__ t,
    const float* __restrict__ loc_w, const float* __restrict__ loc_b,
    const float* __restrict__ shape_w, const float* __restrict__ shape_b,
    const float* __restrict__ offset_w,
    float* __restrict__ out, float* __restrict__ off_ws)
{
    const int p = blockIdx.x * 64 + threadIdx.x;
    const int b = blockIdx.y;
    const float* tb = t + (size_t)b * CC * HWP + p;

    float aloc = 0.f, s0 = 0.f, s1 = 0.f;
    for (int c = 0; c < CC; c++) {
        const float v = tb[(size_t)c * HWP];
        aloc = fmaf(loc_w[c], v, aloc);
        s0   = fmaf(shape_w[c], v, s0);
        s1   = fmaf(shape_w[CC + c], v, s1);
    }
    aloc += loc_b[0];
    s0   += shape_b[0];
    s1   += shape_b[1];

    out[OUT_LOC + b * HWP + p] = aloc;
    out[OUT_SHAPE + (b * 2 + 0) * HWP + p] = s0;
    out[OUT_SHAPE + (b * 2 + 1) * HWP + p] = s1;

    float* ob = off_ws + (size_t)b * (DG * 2 * KK9) * HWP + p;
    for (int o = 0; o < DG * 2 * KK9; o++) {
        ob[(size_t)o * HWP] = fmaf(offset_w[o * 2], s0, offset_w[o * 2 + 1] * s1);
    }
}

// --------------- Kernel 3: deformable conv 3x3 + relu (fp32) ----------------
#define COT3 16
__global__ __launch_bounds__(256) void deform_relu_kernel(
    const float* __restrict__ t, const float* __restrict__ offs,
    const float* __restrict__ w, float* __restrict__ ta)
{
    const int tid = threadIdx.x;
    const int p   = blockIdx.x * 256 + tid;
    const int co0 = blockIdx.y * COT3;
    const int b   = blockIdx.z;
    const int y = p / WW, x = p % WW;

    __shared__ float wsm[COT3 * CG * 9];        // 9216 floats = 36.9 KB

    float acc[COT3];
#pragma unroll
    for (int j = 0; j < COT3; j++) acc[j] = 0.0f;

    const float* ob = offs + (size_t)b * (DG * 2 * KK9) * HWP + p;

    for (int g = 0; g < DG; g++) {
        __syncthreads();
        for (int idx = tid; idx < COT3 * CG * 9; idx += 256) {
            int j  = idx / (CG * 9);
            int r  = idx % (CG * 9);
            int ci = r / 9;
            int k  = r % 9;
            wsm[idx] = w[((size_t)(co0 + j) * CC + g * CG + ci) * 9 + k];
        }
        __syncthreads();

        const float* tg = t + ((size_t)b * CC + g * CG) * HWP;

        for (int k = 0; k < KK9; k++) {
            const float dy = ob[(size_t)((g * KK9 + k) * 2 + 0) * HWP];
            const float dx = ob[(size_t)((g * KK9 + k) * 2 + 1) * HWP];
            const float py = (float)(y + k / 3 - 1) + dy;
            const float px = (float)(x + k % 3 - 1) + dx;
            const float y0f = floorf(py), x0f = floorf(px);
            const float wy = py - y0f, wx = px - x0f;
            const int y0 = (int)y0f, x0 = (int)x0f;
            const int y1 = y0 + 1, x1 = x0 + 1;
            const bool vy0 = (y0 >= 0) && (y0 < HH), vy1 = (y1 >= 0) && (y1 < HH);
            const bool vx0 = (x0 >= 0) && (x0 < WW), vx1 = (x1 >= 0) && (x1 < WW);
            const int y0c = min(max(y0, 0), HH - 1), y1c = min(max(y1, 0), HH - 1);
            const int x0c = min(max(x0, 0), WW - 1), x1c = min(max(x1, 0), WW - 1);
            const int i00 = y0c * WW + x0c, i01 = y0c * WW + x1c;
            const int i10 = y1c * WW + x0c, i11 = y1c * WW + x1c;
            // border handling: clamp address (always valid), zero the weight
            const float w00 = (vy0 && vx0) ? (1.f - wy) * (1.f - wx) : 0.f;
            const float w01 = (vy0 && vx1) ? (1.f - wy) * wx         : 0.f;
            const float w10 = (vy1 && vx0) ? wy * (1.f - wx)         : 0.f;
            const float w11 = (vy1 && vx1) ? wy * wx                 : 0.f;

            for (int ci = 0; ci < CG; ci++) {
                const float* tc = tg + (size_t)ci * HWP;
                float s = w00 * tc[i00];
                s = fmaf(w01, tc[i01], s);
                s = fmaf(w10, tc[i10], s);
                s = fmaf(w11, tc[i11], s);
#pragma unroll
                for (int j = 0; j < COT3; j++)
                    acc[j] = fmaf(s, wsm[(j * CG + ci) * 9 + k], acc[j]);
            }
        }
    }

    float* tab = ta + ((size_t)b * CC + co0) * HWP + p;
#pragma unroll
    for (int j = 0; j < COT3; j++) tab[(size_t)j * HWP] = fmaxf(acc[j], 0.0f);
}

// ------------------- Kernel 4: cls / bbox heads (fused) ---------------------
__global__ __launch_bounds__(64) void heads2_kernel(
    const float* __restrict__ ta,
    const float* __restrict__ cls_w, const float* __restrict__ cls_b,
    const float* __restrict__ bbox_w, const float* __restrict__ bbox_b,
    float* __restrict__ out)
{
    const int p = blockIdx.x * 64 + threadIdx.x;
    const int b = blockIdx.y;
    const float* tb = ta + (size_t)b * CC * HWP + p;

    float ac = 0.f, a0 = 0.f, a1 = 0.f, a2 = 0.f, a3 = 0.f;
    for (int c = 0; c < CC; c++) {
        const float v = tb[(size_t)c * HWP];
        ac = fmaf(cls_w[c], v, ac);
        a0 = fmaf(bbox_w[c], v, a0);
        a1 = fmaf(bbox_w[CC + c], v, a1);
        a2 = fmaf(bbox_w[2 * CC + c], v, a2);
        a3 = fmaf(bbox_w[3 * CC + c], v, a3);
    }
    out[OUT_LOGITS + b * HWP + p] = ac + cls_b[0];
    out[OUT_BBOX + (b * 4 + 0) * HWP + p] = a0 + bbox_b[0];
    out[OUT_BBOX + (b * 4 + 1) * HWP + p] = a1 + bbox_b[1];
    out[OUT_BBOX + (b * 4 + 2) * HWP + p] = a2 + bbox_b[2];
    out[OUT_BBOX + (b * 4 + 3) * HWP + p] = a3 + bbox_b[3];
}

// ----------------------------------------------------------------------------
extern "C" void kernel_launch(void* const* d_in, const int* in_sizes, int n_in,
                              void* d_out, int out_size, void* d_ws, size_t ws_size,
                              hipStream_t stream)
{
    const float* feature  = (const float*)d_in[0];
    const float* conv_w   = (const float*)d_in[1];
    const float* conv_b   = (const float*)d_in[2];
    const float* loc_w    = (const float*)d_in[3];
    const float* loc_b    = (const float*)d_in[4];
    const float* shape_w  = (const float*)d_in[5];
    const float* shape_b  = (const float*)d_in[6];
    const float* offset_w = (const float*)d_in[7];
    const float* adapt_w  = (const float*)d_in[8];
    const float* cls_w    = (const float*)d_in[9];
    const float* cls_b    = (const float*)d_in[10];
    const float* bbox_w   = (const float*)d_in[11];
    const float* bbox_b   = (const float*)d_in[12];
    float* out = (float*)d_out;

    // workspace partition (floats): t[2*256*9216], off[2*72*9216], ta[2*256*9216]
    float* t   = (float*)d_ws;
    float* off = t + (size_t)BB * CC * HWP;                 // +4,718,592
    float* ta  = off + (size_t)BB * (DG * 2 * KK9) * HWP;   // +1,327,104

    // 1) t = relu(conv3x3(feature) + b)
    conv3x3_relu_kernel<<<dim3(HWP / 256, CC / COT1, BB), 256, 0, stream>>>(
        feature, conv_w, conv_b, t);

    // 2) loc, shape_pred (-> d_out), offset (-> ws)
    heads1_kernel<<<dim3(HWP / 64, BB), 64, 0, stream>>>(
        t, loc_w, loc_b, shape_w, shape_b, offset_w, out, off);

    // 3) ta = relu(deform_conv(t, offset))
    deform_relu_kernel<<<dim3(HWP / 256, CC / COT3, BB), 256, 0, stream>>>(
        t, off, adapt_w, ta);

    // 4) logits, bbox (-> d_out)
    heads2_kernel<<<dim3(HWP / 64, BB), 64, 0, stream>>>(
        ta, cls_w, cls_b, bbox_w, bbox_b, out);
}

// Round 2
// 393.934 us; speedup vs baseline: 7.2749x; 7.2749x over previous
//
#include <hip/hip_runtime.h>
#include <hip/hip_bf16.h>

// Problem constants
#define BB 2
#define CC 256
#define HH 96
#define WW 96
#define HWP (HH*WW)        // 9216
#define K1 2304            // 256*9, GEMM K for both convs
#define NKT 36             // K1/64 k-steps

// d_out layout: logits[2,1,96,96], bbox[2,4,96,96], shape[2,2,96,96], loc[2,1,96,96]
#define OUT_LOGITS 0
#define OUT_BBOX   (2*1*HWP)
#define OUT_SHAPE  (OUT_BBOX + 2*4*HWP)
#define OUT_LOC    (OUT_SHAPE + 2*2*HWP)

typedef __attribute__((ext_vector_type(8))) short short8v;   // 8 bf16 (4 VGPRs)
typedef __attribute__((ext_vector_type(4))) float f32x4;

typedef const __attribute__((address_space(1))) void* gptr_t;
typedef __attribute__((address_space(3))) void* lptr_t;
#define GLOAD16(g, l) __builtin_amdgcn_global_load_lds((gptr_t)(g), (lptr_t)(l), 16, 0, 0)

__device__ __forceinline__ float bf2f(unsigned short u) {
    return __uint_as_float(((unsigned)u) << 16);
}
__device__ __forceinline__ unsigned short f2bf(float f) {
    unsigned u = __float_as_uint(f);
    u += 0x7FFFu + ((u >> 16) & 1u);           // round-to-nearest-even
    return (unsigned short)(u >> 16);
}

// ---------------- prep: weights -> bf16 (W1 k-order (kk,ci); W2 flat) -------
__global__ __launch_bounds__(256) void prep_kernel(
    const float* __restrict__ conv_w, const float* __restrict__ adapt_w,
    unsigned short* __restrict__ W1, unsigned short* __restrict__ W2,
    unsigned short* __restrict__ zp)
{
    const int t = blockIdx.x * 256 + threadIdx.x;
    if (t < 1024) zp[t] = 0;                    // zero page (ws is re-poisoned!)
    if (t < CC * K1) {
        W2[t] = f2bf(adapt_w[t]);               // k = ci*9+kk (matches X2 rows)
        const int co = t / K1, r = t % K1;
        const int kk = r >> 8, ci = r & 255;    // k = kk*256+ci for conv1
        W1[t] = f2bf(conv_w[co * K1 + ci * 9 + kk]);
    }
}

// ------------- transpose feature [b][c][p] fp32 -> f_cf [b][p][c] bf16 ------
__global__ __launch_bounds__(256) void transpose_kernel(
    const float* __restrict__ f, unsigned short* __restrict__ fcf)
{
    __shared__ unsigned short tile[64][66];     // +2 pad: conflict-free col reads
    const int p0 = blockIdx.x * 64;
    const int b  = blockIdx.y;
    const int tx = threadIdx.x & 63, ty = threadIdx.x >> 6;
    for (int cc = 0; cc < 4; cc++) {
        __syncthreads();
#pragma unroll
        for (int ii = 0; ii < 16; ii++) {
            const int cl = ii * 4 + ty;
            tile[cl][tx] = f2bf(f[((size_t)b * CC + cc * 64 + cl) * HWP + p0 + tx]);
        }
        __syncthreads();
#pragma unroll
        for (int ii = 0; ii < 16; ii++) {
            const int pl = ii * 4 + ty;
            fcf[((size_t)(b * HWP + p0 + pl)) * CC + cc * 64 + tx] = tile[tx][pl];
        }
    }
}

// --------- GEMM1: t = relu(W1[256,K1] x im2col(f_cf) + bias), bf16 MFMA -----
// 128x128 tile, BK=64, 4 waves (2x2), 16x16x32 MFMA, global_load_lds staging.
// LDS layout (A and B): slot s = kc*128 + row (16B slots, kc = k_local/8).
__global__ __launch_bounds__(256) void gemm1_kernel(
    const unsigned short* __restrict__ W1, const unsigned short* __restrict__ fcf,
    const float* __restrict__ bias, const unsigned short* __restrict__ zp,
    unsigned short* __restrict__ tcf)
{
    __shared__ short As[8192];                  // 128 rows x 64 k bf16 = 16 KB
    __shared__ short Bs[8192];
    const int tid  = threadIdx.x;
    const int lane = tid & 63, w = tid >> 6;
    const int quad = lane >> 4, r15 = lane & 15;
    const int n0  = blockIdx.x * 128;
    const int co0 = blockIdx.y * 128;
    const int b   = blockIdx.z;
    const int wm = w >> 1, wn = w & 1;

    f32x4 acc[4][4];
#pragma unroll
    for (int i = 0; i < 4; i++)
#pragma unroll
        for (int j = 0; j < 4; j++) acc[i][j] = (f32x4){0.f, 0.f, 0.f, 0.f};

    for (int kt = 0; kt < NKT; kt++) {
        const int k0 = kt * 64;
#pragma unroll
        for (int i = 0; i < 4; i++) {
            const int kc    = w * 2 + (i >> 1);         // wave-uniform
            const int row   = ((i & 1) << 6) + lane;
            const int sbase = w * 256 + i * 64;          // lds dest = base + lane*16
            // A: W1 row co0+row, k-chunk
            GLOAD16(W1 + (size_t)(co0 + row) * K1 + k0 + kc * 8, &As[sbase * 8]);
            // B: implicit im2col row p=n0+row, k=(kk,ci)
            const int k   = k0 + kc * 8;
            const int kk  = k >> 8;
            const int ci0 = k & 255;
            const int p = n0 + row;
            const int y = p / WW, x = p % WW;
            const int yy = y + kk / 3 - 1, xx = x + kk % 3 - 1;
            const bool ok = (yy >= 0) && (yy < HH) && (xx >= 0) && (xx < WW);
            const unsigned short* gb = ok
                ? fcf + ((size_t)(b * HWP + yy * WW + xx)) * CC + ci0
                : zp;
            GLOAD16(gb, &Bs[sbase * 8]);
        }
        __syncthreads();
#pragma unroll
        for (int ks = 0; ks < 2; ks++) {
            short8v a[4], bf[4];
#pragma unroll
            for (int i = 0; i < 4; i++)
                a[i] = *(const short8v*)&As[(((ks * 4 + quad) * 128) + wm * 64 + i * 16 + r15) * 8];
#pragma unroll
            for (int j = 0; j < 4; j++)
                bf[j] = *(const short8v*)&Bs[(((ks * 4 + quad) * 128) + wn * 64 + j * 16 + r15) * 8];
#pragma unroll
            for (int i = 0; i < 4; i++)
#pragma unroll
                for (int j = 0; j < 4; j++)
                    acc[i][j] = __builtin_amdgcn_mfma_f32_16x16x32_bf16(a[i], bf[j], acc[i][j], 0, 0, 0);
        }
        __syncthreads();
    }
    // epilogue: bias + relu -> t_cf[b][p][c] bf16 (C/D map: col=lane&15, row=quad*4+reg)
#pragma unroll
    for (int i = 0; i < 4; i++) {
        const int m = co0 + wm * 64 + i * 16 + quad * 4;
        const float b0 = bias[m], b1 = bias[m + 1], b2 = bias[m + 2], b3 = bias[m + 3];
#pragma unroll
        for (int j = 0; j < 4; j++) {
            const int p = n0 + wn * 64 + j * 16 + r15;
            ushort4 st;
            st.x = f2bf(fmaxf(acc[i][j][0] + b0, 0.f));
            st.y = f2bf(fmaxf(acc[i][j][1] + b1, 0.f));
            st.z = f2bf(fmaxf(acc[i][j][2] + b2, 0.f));
            st.w = f2bf(fmaxf(acc[i][j][3] + b3, 0.f));
            *(ushort4*)(tcf + ((size_t)(b * HWP + p)) * CC + m) = st;
        }
    }
}

// ------------- heads1: loc/shape (fp32) + offset field from t_cf ------------
__global__ __launch_bounds__(256) void heads1_kernel(
    const unsigned short* __restrict__ tcf,
    const float* __restrict__ loc_w, const float* __restrict__ loc_b,
    const float* __restrict__ shape_w, const float* __restrict__ shape_b,
    const float* __restrict__ offset_w,
    float* __restrict__ out, float* __restrict__ off)
{
    const int p = blockIdx.x * 256 + threadIdx.x;
    const int b = blockIdx.y;
    const unsigned short* row = tcf + (size_t)(b * HWP + p) * CC;
    float aloc = 0.f, s0 = 0.f, s1 = 0.f;
    for (int c = 0; c < CC; c += 8) {
        short8v v = *(const short8v*)&row[c];
#pragma unroll
        for (int k = 0; k < 8; k++) {
            const float fv = bf2f((unsigned short)v[k]);
            aloc = fmaf(loc_w[c + k], fv, aloc);
            s0   = fmaf(shape_w[c + k], fv, s0);
            s1   = fmaf(shape_w[CC + c + k], fv, s1);
        }
    }
    aloc += loc_b[0]; s0 += shape_b[0]; s1 += shape_b[1];
    out[OUT_LOC + b * HWP + p] = aloc;
    out[OUT_SHAPE + (b * 2 + 0) * HWP + p] = s0;
    out[OUT_SHAPE + (b * 2 + 1) * HWP + p] = s1;
    float* ob = off + (size_t)b * 72 * HWP + p;
    for (int o = 0; o < 72; o++)
        ob[(size_t)o * HWP] = fmaf(offset_w[o * 2], s0, offset_w[o * 2 + 1] * s1);
}

// --------- sampling: bilinear gather -> X2^T [p][k=ci*9+kk] bf16 ------------
// one wave per pixel; lane = channel-within-group (coalesced 128B reads).
__global__ __launch_bounds__(256) void sample_kernel(
    const unsigned short* __restrict__ tcf, const float* __restrict__ off,
    unsigned short* __restrict__ X2, int b)
{
    __shared__ unsigned short sbuf[4][K1];      // wave-private row buffers
    const int lane = threadIdx.x & 63, w = threadIdx.x >> 6;
    const int p = blockIdx.x * 4 + w;
    const int y = p / WW, x = p % WW;
    const float* ob = off + (size_t)b * 72 * HWP + p;
    const unsigned short* tb = tcf + (size_t)b * HWP * CC;

    for (int g = 0; g < 4; g++) {
        const unsigned short* tg = tb + g * 64 + lane;
#pragma unroll
        for (int kk = 0; kk < 9; kk++) {
            const float dy = ob[(size_t)((g * 9 + kk) * 2 + 0) * HWP];
            const float dx = ob[(size_t)((g * 9 + kk) * 2 + 1) * HWP];
            const float py = (float)(y + kk / 3 - 1) + dy;
            const float px = (float)(x + kk % 3 - 1) + dx;
            const float y0f = floorf(py), x0f = floorf(px);
            const float wy = py - y0f, wx = px - x0f;
            const int y0 = (int)y0f, x0 = (int)x0f;
            const int y1 = y0 + 1, x1 = x0 + 1;
            const bool vy0 = (y0 >= 0) && (y0 < HH), vy1 = (y1 >= 0) && (y1 < HH);
            const bool vx0 = (x0 >= 0) && (x0 < WW), vx1 = (x1 >= 0) && (x1 < WW);
            const int y0c = min(max(y0, 0), HH - 1), y1c = min(max(y1, 0), HH - 1);
            const int x0c = min(max(x0, 0), WW - 1), x1c = min(max(x1, 0), WW - 1);
            const float w00 = (vy0 && vx0) ? (1.f - wy) * (1.f - wx) : 0.f;
            const float w01 = (vy0 && vx1) ? (1.f - wy) * wx         : 0.f;
            const float w10 = (vy1 && vx0) ? wy * (1.f - wx)         : 0.f;
            const float w11 = (vy1 && vx1) ? wy * wx                 : 0.f;
            const float v00 = bf2f(tg[(size_t)(y0c * WW + x0c) * CC]);
            const float v01 = bf2f(tg[(size_t)(y0c * WW + x1c) * CC]);
            const float v10 = bf2f(tg[(size_t)(y1c * WW + x0c) * CC]);
            const float v11 = bf2f(tg[(size_t)(y1c * WW + x1c) * CC]);
            float val = w00 * v00;
            val = fmaf(w01, v01, val);
            val = fmaf(w10, v10, val);
            val = fmaf(w11, v11, val);
            sbuf[w][(g * 64 + lane) * 9 + kk] = f2bf(val);
        }
    }
    // stream row out coalesced: 2304 ushorts = 4*512 + 256
    unsigned short* dst = X2 + (size_t)p * K1;
    const unsigned short* src = sbuf[w];
#pragma unroll
    for (int c = 0; c < 4; c++)
        *(short8v*)&dst[c * 512 + lane * 8] = *(const short8v*)&src[c * 512 + lane * 8];
    *(ushort4*)&dst[2048 + lane * 4] = *(const ushort4*)&src[2048 + lane * 4];
}

// --------- GEMM2: ta = relu(W2[256,K1] x X2^T), bf16 MFMA (per batch) -------
__global__ __launch_bounds__(256) void gemm2_kernel(
    const unsigned short* __restrict__ W2, const unsigned short* __restrict__ X2,
    unsigned short* __restrict__ tacf, int b)
{
    __shared__ short As[8192];
    __shared__ short Bs[8192];
    const int tid  = threadIdx.x;
    const int lane = tid & 63, w = tid >> 6;
    const int quad = lane >> 4, r15 = lane & 15;
    const int n0  = blockIdx.x * 128;
    const int co0 = blockIdx.y * 128;
    const int wm = w >> 1, wn = w & 1;

    f32x4 acc[4][4];
#pragma unroll
    for (int i = 0; i < 4; i++)
#pragma unroll
        for (int j = 0; j < 4; j++) acc[i][j] = (f32x4){0.f, 0.f, 0.f, 0.f};

    for (int kt = 0; kt < NKT; kt++) {
        const int k0 = kt * 64;
#pragma unroll
        for (int i = 0; i < 4; i++) {
            const int kc    = w * 2 + (i >> 1);
            const int row   = ((i & 1) << 6) + lane;
            const int sbase = w * 256 + i * 64;
            GLOAD16(W2 + (size_t)(co0 + row) * K1 + k0 + kc * 8, &As[sbase * 8]);
            GLOAD16(X2 + (size_t)(n0 + row) * K1 + k0 + kc * 8, &Bs[sbase * 8]);
        }
        __syncthreads();
#pragma unroll
        for (int ks = 0; ks < 2; ks++) {
            short8v a[4], bf[4];
#pragma unroll
            for (int i = 0; i < 4; i++)
                a[i] = *(const short8v*)&As[(((ks * 4 + quad) * 128) + wm * 64 + i * 16 + r15) * 8];
#pragma unroll
            for (int j = 0; j < 4; j++)
                bf[j] = *(const short8v*)&Bs[(((ks * 4 + quad) * 128) + wn * 64 + j * 16 + r15) * 8];
#pragma unroll
            for (int i = 0; i < 4; i++)
#pragma unroll
                for (int j = 0; j < 4; j++)
                    acc[i][j] = __builtin_amdgcn_mfma_f32_16x16x32_bf16(a[i], bf[j], acc[i][j], 0, 0, 0);
        }
        __syncthreads();
    }
#pragma unroll
    for (int i = 0; i < 4; i++) {
        const int m = co0 + wm * 64 + i * 16 + quad * 4;
#pragma unroll
        for (int j = 0; j < 4; j++) {
            const int p = n0 + wn * 64 + j * 16 + r15;
            ushort4 st;
            st.x = f2bf(fmaxf(acc[i][j][0], 0.f));
            st.y = f2bf(fmaxf(acc[i][j][1], 0.f));
            st.z = f2bf(fmaxf(acc[i][j][2], 0.f));
            st.w = f2bf(fmaxf(acc[i][j][3], 0.f));
            *(ushort4*)(tacf + ((size_t)(b * HWP + p)) * CC + m) = st;
        }
    }
}

// ------------------- heads2: cls/bbox from ta_cf (fp32) ---------------------
__global__ __launch_bounds__(256) void heads2_kernel(
    const unsigned short* __restrict__ tacf,
    const float* __restrict__ cls_w, const float* __restrict__ cls_b,
    const float* __restrict__ bbox_w, const float* __restrict__ bbox_b,
    float* __restrict__ out)
{
    const int p = blockIdx.x * 256 + threadIdx.x;
    const int b = blockIdx.y;
    const unsigned short* row = tacf + (size_t)(b * HWP + p) * CC;
    float ac = 0.f, a0 = 0.f, a1 = 0.f, a2 = 0.f, a3 = 0.f;
    for (int c = 0; c < CC; c += 8) {
        short8v v = *(const short8v*)&row[c];
#pragma unroll
        for (int k = 0; k < 8; k++) {
            const float fv = bf2f((unsigned short)v[k]);
            ac = fmaf(cls_w[c + k], fv, ac);
            a0 = fmaf(bbox_w[c + k], fv, a0);
            a1 = fmaf(bbox_w[CC + c + k], fv, a1);
            a2 = fmaf(bbox_w[2 * CC + c + k], fv, a2);
            a3 = fmaf(bbox_w[3 * CC + c + k], fv, a3);
        }
    }
    out[OUT_LOGITS + b * HWP + p] = ac + cls_b[0];
    out[OUT_BBOX + (b * 4 + 0) * HWP + p] = a0 + bbox_b[0];
    out[OUT_BBOX + (b * 4 + 1) * HWP + p] = a1 + bbox_b[1];
    out[OUT_BBOX + (b * 4 + 2) * HWP + p] = a2 + bbox_b[2];
    out[OUT_BBOX + (b * 4 + 3) * HWP + p] = a3 + bbox_b[3];
}

// ----------------------------------------------------------------------------
extern "C" void kernel_launch(void* const* d_in, const int* in_sizes, int n_in,
                              void* d_out, int out_size, void* d_ws, size_t ws_size,
                              hipStream_t stream)
{
    const float* feature  = (const float*)d_in[0];
    const float* conv_w   = (const float*)d_in[1];
    const float* conv_b   = (const float*)d_in[2];
    const float* loc_w    = (const float*)d_in[3];
    const float* loc_b    = (const float*)d_in[4];
    const float* shape_w  = (const float*)d_in[5];
    const float* shape_b  = (const float*)d_in[6];
    const float* offset_w = (const float*)d_in[7];
    const float* adapt_w  = (const float*)d_in[8];
    const float* cls_w    = (const float*)d_in[9];
    const float* cls_b    = (const float*)d_in[10];
    const float* bbox_w   = (const float*)d_in[11];
    const float* bbox_b   = (const float*)d_in[12];
    float* out = (float*)d_out;

    // workspace partition (~69 MB)
    float*          off = (float*)d_ws;                        // 2*72*9216 fp32
    unsigned short* tcf = (unsigned short*)(off + 2 * 72 * HWP);   // 2*9216*256 bf16
    unsigned short* fcf = tcf + (size_t)2 * HWP * CC;              // 2*9216*256 bf16
    unsigned short* tacf = fcf;   // alias: f_cf dead after gemm1, ta written after
    unsigned short* W1  = fcf + (size_t)2 * HWP * CC;              // 256*2304 bf16
    unsigned short* W2  = W1 + (size_t)CC * K1;
    unsigned short* zp  = W2 + (size_t)CC * K1;                    // 1024 zeros
    unsigned short* X2  = zp + 1024;                               // 9216*2304 bf16 (per batch)

    prep_kernel<<<(CC * K1 + 255) / 256, 256, 0, stream>>>(conv_w, adapt_w, W1, W2, zp);
    transpose_kernel<<<dim3(HWP / 64, BB), 256, 0, stream>>>(feature, fcf);
    gemm1_kernel<<<dim3(HWP / 128, 2, BB), 256, 0, stream>>>(W1, fcf, conv_b, zp, tcf);
    heads1_kernel<<<dim3(HWP / 256, BB), 256, 0, stream>>>(
        tcf, loc_w, loc_b, shape_w, shape_b, offset_w, out, off);
    for (int b = 0; b < BB; b++) {
        sample_kernel<<<HWP / 4, 256, 0, stream>>>(tcf, off, X2, b);
        gemm2_kernel<<<dim3(HWP / 128, 2), 256, 0, stream>>>(W2, X2, tacf, b);
    }
    heads2_kernel<<<dim3(HWP / 256, BB), 256, 0, stream>>>(
        tacf, cls_w, cls_b, bbox_w, bbox_b, out);
}

// Round 3
// 356.779 us; speedup vs baseline: 8.0325x; 1.1041x over previous
//
#include <hip/hip_runtime.h>
#include <hip/hip_bf16.h>

// Problem constants
#define BB 2
#define CC 256
#define HH 96
#define WW 96
#define HWP (HH*WW)        // 9216
#define NTOT (BB*HWP)      // 18432 flattened (b,p)
#define K1 2304            // 256*9, GEMM K for both convs
#define NKT 36             // K1/64 k-steps

// d_out layout: logits[2,1,96,96], bbox[2,4,96,96], shape[2,2,96,96], loc[2,1,96,96]
#define OUT_LOGITS 0
#define OUT_BBOX   (2*1*HWP)
#define OUT_SHAPE  (OUT_BBOX + 2*4*HWP)
#define OUT_LOC    (OUT_SHAPE + 2*2*HWP)

typedef __attribute__((ext_vector_type(8))) short short8v;   // 8 bf16 (4 VGPRs)
typedef __attribute__((ext_vector_type(4))) float f32x4;

typedef const __attribute__((address_space(1))) void* gptr_t;
typedef __attribute__((address_space(3))) void* lptr_t;
#define GLOAD16(g, l) __builtin_amdgcn_global_load_lds((gptr_t)(g), (lptr_t)(l), 16, 0, 0)

__device__ __forceinline__ float bf2f(unsigned short u) {
    return __uint_as_float(((unsigned)u) << 16);
}
__device__ __forceinline__ unsigned short f2bf(float f) {
    unsigned u = __float_as_uint(f);
    u += 0x7FFFu + ((u >> 16) & 1u);           // round-to-nearest-even
    return (unsigned short)(u >> 16);
}

// ---------------- prep: weights -> bf16 (W1 k-order (kk,ci); W2 flat) -------
__global__ __launch_bounds__(256) void prep_kernel(
    const float* __restrict__ conv_w, const float* __restrict__ adapt_w,
    unsigned short* __restrict__ W1, unsigned short* __restrict__ W2,
    unsigned short* __restrict__ zp)
{
    const int t = blockIdx.x * 256 + threadIdx.x;
    if (t < 1024) zp[t] = 0;                    // zero page (ws is re-poisoned!)
    if (t < CC * K1) {
        W2[t] = f2bf(adapt_w[t]);               // k = ci*9+kk (matches X2 rows)
        const int co = t / K1, r = t % K1;
        const int kk = r >> 8, ci = r & 255;    // k = kk*256+ci for conv1
        W1[t] = f2bf(conv_w[co * K1 + ci * 9 + kk]);
    }
}

// ------------- transpose feature [b][c][p] fp32 -> f_cf [b][p][c] bf16 ------
__global__ __launch_bounds__(256) void transpose_kernel(
    const float* __restrict__ f, unsigned short* __restrict__ fcf)
{
    __shared__ unsigned short tile[64][66];     // +2 pad: conflict-free col reads
    const int p0 = blockIdx.x * 64;
    const int b  = blockIdx.y;
    const int tx = threadIdx.x & 63, ty = threadIdx.x >> 6;
    for (int cc = 0; cc < 4; cc++) {
        __syncthreads();
#pragma unroll
        for (int ii = 0; ii < 16; ii++) {
            const int cl = ii * 4 + ty;
            tile[cl][tx] = f2bf(f[((size_t)b * CC + cc * 64 + cl) * HWP + p0 + tx]);
        }
        __syncthreads();
#pragma unroll
        for (int ii = 0; ii < 16; ii++) {
            const int pl = ii * 4 + ty;
            fcf[((size_t)(b * HWP + p0 + pl)) * CC + cc * 64 + tx] = tile[tx][pl];
        }
    }
}

// --------- GEMM1: t = relu(W1[256,K1] x im2col(f_cf) + bias), bf16 MFMA -----
// 128M x 64N tile, BK=64, 4 waves (2x2: wm over M-halves, wn over N-halves),
// 16x16x32 MFMA, global_load_lds staging; batch flattened into N (576 blocks).
__global__ __launch_bounds__(256) void gemm1_kernel(
    const unsigned short* __restrict__ W1, const unsigned short* __restrict__ fcf,
    const float* __restrict__ bias, const unsigned short* __restrict__ zp,
    unsigned short* __restrict__ tcf)
{
    __shared__ short As[8192];                  // 128 rows x 64 k = 16 KB
    __shared__ short Bs[4096];                  // 64 rows x 64 k = 8 KB
    const int tid  = threadIdx.x;
    const int lane = tid & 63, w = tid >> 6;
    const int quad = lane >> 4, r15 = lane & 15;
    const int n0  = blockIdx.x * 64;            // flattened (b,p); 9216%64==0
    const int co0 = blockIdx.y * 128;
    const int wm = w >> 1, wn = w & 1;

    // B row geometry (uniform per thread; whole block is in one batch)
    const int nb = n0 + lane;
    const int b  = nb / HWP;
    const int p  = nb - b * HWP;
    const int y = p / WW, x = p % WW;

    f32x4 acc[4][2];
#pragma unroll
    for (int i = 0; i < 4; i++)
#pragma unroll
        for (int j = 0; j < 2; j++) acc[i][j] = (f32x4){0.f, 0.f, 0.f, 0.f};

    for (int kt = 0; kt < NKT; kt++) {
        const int k0 = kt * 64;
#pragma unroll
        for (int i = 0; i < 4; i++) {           // A: 4 chunks/thread
            const int kc    = w * 2 + (i >> 1);
            const int row   = ((i & 1) << 6) + lane;
            const int sbase = w * 256 + i * 64;
            GLOAD16(W1 + (size_t)(co0 + row) * K1 + k0 + kc * 8, &As[sbase * 8]);
        }
#pragma unroll
        for (int i = 0; i < 2; i++) {           // B: 2 chunks/thread, implicit im2col
            const int kc    = w * 2 + i;
            const int sbase = w * 128 + i * 64;
            const int k   = k0 + kc * 8;
            const int kk  = k >> 8;
            const int ci0 = k & 255;
            const int yy = y + kk / 3 - 1, xx = x + kk % 3 - 1;
            const bool ok = (yy >= 0) && (yy < HH) && (xx >= 0) && (xx < WW);
            const unsigned short* gb = ok
                ? fcf + ((size_t)(b * HWP + yy * WW + xx)) * CC + ci0
                : zp;
            GLOAD16(gb, &Bs[sbase * 8]);
        }
        __syncthreads();
#pragma unroll
        for (int ks = 0; ks < 2; ks++) {
            short8v a[4], bf[2];
#pragma unroll
            for (int i = 0; i < 4; i++)
                a[i] = *(const short8v*)&As[(((ks * 4 + quad) * 128) + wm * 64 + i * 16 + r15) * 8];
#pragma unroll
            for (int j = 0; j < 2; j++)
                bf[j] = *(const short8v*)&Bs[(((ks * 4 + quad) * 64) + wn * 32 + j * 16 + r15) * 8];
#pragma unroll
            for (int i = 0; i < 4; i++)
#pragma unroll
                for (int j = 0; j < 2; j++)
                    acc[i][j] = __builtin_amdgcn_mfma_f32_16x16x32_bf16(a[i], bf[j], acc[i][j], 0, 0, 0);
        }
        __syncthreads();
    }
    // epilogue: bias + relu -> t_cf[n][c] bf16 (C/D map: col=lane&15, row=quad*4+reg)
#pragma unroll
    for (int i = 0; i < 4; i++) {
        const int m = co0 + wm * 64 + i * 16 + quad * 4;
        const float b0 = bias[m], b1 = bias[m + 1], b2 = bias[m + 2], b3 = bias[m + 3];
#pragma unroll
        for (int j = 0; j < 2; j++) {
            const int n = n0 + wn * 32 + j * 16 + r15;
            ushort4 st;
            st.x = f2bf(fmaxf(acc[i][j][0] + b0, 0.f));
            st.y = f2bf(fmaxf(acc[i][j][1] + b1, 0.f));
            st.z = f2bf(fmaxf(acc[i][j][2] + b2, 0.f));
            st.w = f2bf(fmaxf(acc[i][j][3] + b3, 0.f));
            *(ushort4*)(tcf + (size_t)n * CC + m) = st;
        }
    }
}

// ------------- heads1: loc/shape (fp32) + offset field from t_cf ------------
__global__ __launch_bounds__(256) void heads1_kernel(
    const unsigned short* __restrict__ tcf,
    const float* __restrict__ loc_w, const float* __restrict__ loc_b,
    const float* __restrict__ shape_w, const float* __restrict__ shape_b,
    const float* __restrict__ offset_w,
    float* __restrict__ out, float* __restrict__ off)
{
    const int p = blockIdx.x * 256 + threadIdx.x;
    const int b = blockIdx.y;
    const unsigned short* row = tcf + (size_t)(b * HWP + p) * CC;
    float aloc = 0.f, s0 = 0.f, s1 = 0.f;
    for (int c = 0; c < CC; c += 8) {
        short8v v = *(const short8v*)&row[c];
#pragma unroll
        for (int k = 0; k < 8; k++) {
            const float fv = bf2f((unsigned short)v[k]);
            aloc = fmaf(loc_w[c + k], fv, aloc);
            s0   = fmaf(shape_w[c + k], fv, s0);
            s1   = fmaf(shape_w[CC + c + k], fv, s1);
        }
    }
    aloc += loc_b[0]; s0 += shape_b[0]; s1 += shape_b[1];
    out[OUT_LOC + b * HWP + p] = aloc;
    out[OUT_SHAPE + (b * 2 + 0) * HWP + p] = s0;
    out[OUT_SHAPE + (b * 2 + 1) * HWP + p] = s1;
    float* ob = off + (size_t)b * 72 * HWP + p;
    for (int o = 0; o < 72; o++)
        ob[(size_t)o * HWP] = fmaf(offset_w[o * 2], s0, offset_w[o * 2 + 1] * s1);
}

// --------- sampling: bilinear gather -> X2^T [n][k=ci*9+kk] bf16 ------------
// one wave per pixel; lane = channel-within-group (coalesced 128B reads).
// b = blockIdx.y + bOff; X2 indexed by local blockIdx.y (per-launch buffer).
__global__ __launch_bounds__(256) void sample_kernel(
    const unsigned short* __restrict__ tcf, const float* __restrict__ off,
    unsigned short* __restrict__ X2, int bOff)
{
    __shared__ unsigned short sbuf[4][K1];      // wave-private row buffers
    const int lane = threadIdx.x & 63, w = threadIdx.x >> 6;
    const int p = blockIdx.x * 4 + w;
    const int b = blockIdx.y + bOff;
    const int y = p / WW, x = p % WW;
    const float* ob = off + (size_t)b * 72 * HWP + p;
    const unsigned short* tb = tcf + (size_t)b * HWP * CC;

    for (int g = 0; g < 4; g++) {
        const unsigned short* tg = tb + g * 64 + lane;
#pragma unroll
        for (int kk = 0; kk < 9; kk++) {
            const float dy = ob[(size_t)((g * 9 + kk) * 2 + 0) * HWP];
            const float dx = ob[(size_t)((g * 9 + kk) * 2 + 1) * HWP];
            const float py = (float)(y + kk / 3 - 1) + dy;
            const float px = (float)(x + kk % 3 - 1) + dx;
            const float y0f = floorf(py), x0f = floorf(px);
            const float wy = py - y0f, wx = px - x0f;
            const int y0 = (int)y0f, x0 = (int)x0f;
            const int y1 = y0 + 1, x1 = x0 + 1;
            const bool vy0 = (y0 >= 0) && (y0 < HH), vy1 = (y1 >= 0) && (y1 < HH);
            const bool vx0 = (x0 >= 0) && (x0 < WW), vx1 = (x1 >= 0) && (x1 < WW);
            const int y0c = min(max(y0, 0), HH - 1), y1c = min(max(y1, 0), HH - 1);
            const int x0c = min(max(x0, 0), WW - 1), x1c = min(max(x1, 0), WW - 1);
            const float w00 = (vy0 && vx0) ? (1.f - wy) * (1.f - wx) : 0.f;
            const float w01 = (vy0 && vx1) ? (1.f - wy) * wx         : 0.f;
            const float w10 = (vy1 && vx0) ? wy * (1.f - wx)         : 0.f;
            const float w11 = (vy1 && vx1) ? wy * wx                 : 0.f;
            const float v00 = bf2f(tg[(size_t)(y0c * WW + x0c) * CC]);
            const float v01 = bf2f(tg[(size_t)(y0c * WW + x1c) * CC]);
            const float v10 = bf2f(tg[(size_t)(y1c * WW + x0c) * CC]);
            const float v11 = bf2f(tg[(size_t)(y1c * WW + x1c) * CC]);
            float val = w00 * v00;
            val = fmaf(w01, v01, val);
            val = fmaf(w10, v10, val);
            val = fmaf(w11, v11, val);
            sbuf[w][(g * 64 + lane) * 9 + kk] = f2bf(val);
        }
    }
    // stream row out coalesced: 2304 ushorts = 4*512 + 256
    unsigned short* dst = X2 + ((size_t)blockIdx.y * HWP + p) * K1;
    const unsigned short* src = sbuf[w];
#pragma unroll
    for (int c = 0; c < 4; c++)
        *(short8v*)&dst[c * 512 + lane * 8] = *(const short8v*)&src[c * 512 + lane * 8];
    *(ushort4*)&dst[2048 + lane * 4] = *(const ushort4*)&src[2048 + lane * 4];
}

// --------- GEMM2: ta = relu(W2[256,K1] x X2^T), bf16 MFMA, 128x64 tile ------
__global__ __launch_bounds__(256) void gemm2_kernel(
    const unsigned short* __restrict__ W2, const unsigned short* __restrict__ X2,
    unsigned short* __restrict__ tacf, int nBase)
{
    __shared__ short As[8192];
    __shared__ short Bs[4096];
    const int tid  = threadIdx.x;
    const int lane = tid & 63, w = tid >> 6;
    const int quad = lane >> 4, r15 = lane & 15;
    const int n0  = blockIdx.x * 64;            // local row in X2
    const int co0 = blockIdx.y * 128;
    const int wm = w >> 1, wn = w & 1;

    f32x4 acc[4][2];
#pragma unroll
    for (int i = 0; i < 4; i++)
#pragma unroll
        for (int j = 0; j < 2; j++) acc[i][j] = (f32x4){0.f, 0.f, 0.f, 0.f};

    for (int kt = 0; kt < NKT; kt++) {
        const int k0 = kt * 64;
#pragma unroll
        for (int i = 0; i < 4; i++) {
            const int kc    = w * 2 + (i >> 1);
            const int row   = ((i & 1) << 6) + lane;
            const int sbase = w * 256 + i * 64;
            GLOAD16(W2 + (size_t)(co0 + row) * K1 + k0 + kc * 8, &As[sbase * 8]);
        }
#pragma unroll
        for (int i = 0; i < 2; i++) {
            const int kc    = w * 2 + i;
            const int sbase = w * 128 + i * 64;
            GLOAD16(X2 + (size_t)(n0 + lane) * K1 + k0 + kc * 8, &Bs[sbase * 8]);
        }
        __syncthreads();
#pragma unroll
        for (int ks = 0; ks < 2; ks++) {
            short8v a[4], bf[2];
#pragma unroll
            for (int i = 0; i < 4; i++)
                a[i] = *(const short8v*)&As[(((ks * 4 + quad) * 128) + wm * 64 + i * 16 + r15) * 8];
#pragma unroll
            for (int j = 0; j < 2; j++)
                bf[j] = *(const short8v*)&Bs[(((ks * 4 + quad) * 64) + wn * 32 + j * 16 + r15) * 8];
#pragma unroll
            for (int i = 0; i < 4; i++)
#pragma unroll
                for (int j = 0; j < 2; j++)
                    acc[i][j] = __builtin_amdgcn_mfma_f32_16x16x32_bf16(a[i], bf[j], acc[i][j], 0, 0, 0);
        }
        __syncthreads();
    }
#pragma unroll
    for (int i = 0; i < 4; i++) {
        const int m = co0 + wm * 64 + i * 16 + quad * 4;
#pragma unroll
        for (int j = 0; j < 2; j++) {
            const int n = nBase + n0 + wn * 32 + j * 16 + r15;
            ushort4 st;
            st.x = f2bf(fmaxf(acc[i][j][0], 0.f));
            st.y = f2bf(fmaxf(acc[i][j][1], 0.f));
            st.z = f2bf(fmaxf(acc[i][j][2], 0.f));
            st.w = f2bf(fmaxf(acc[i][j][3], 0.f));
            *(ushort4*)(tacf + (size_t)n * CC + m) = st;
        }
    }
}

// ------------------- heads2: cls/bbox from ta_cf (fp32) ---------------------
__global__ __launch_bounds__(256) void heads2_kernel(
    const unsigned short* __restrict__ tacf,
    const float* __restrict__ cls_w, const float* __restrict__ cls_b,
    const float* __restrict__ bbox_w, const float* __restrict__ bbox_b,
    float* __restrict__ out)
{
    const int p = blockIdx.x * 256 + threadIdx.x;
    const int b = blockIdx.y;
    const unsigned short* row = tacf + (size_t)(b * HWP + p) * CC;
    float ac = 0.f, a0 = 0.f, a1 = 0.f, a2 = 0.f, a3 = 0.f;
    for (int c = 0; c < CC; c += 8) {
        short8v v = *(const short8v*)&row[c];
#pragma unroll
        for (int k = 0; k < 8; k++) {
            const float fv = bf2f((unsigned short)v[k]);
            ac = fmaf(cls_w[c + k], fv, ac);
            a0 = fmaf(bbox_w[c + k], fv, a0);
            a1 = fmaf(bbox_w[CC + c + k], fv, a1);
            a2 = fmaf(bbox_w[2 * CC + c + k], fv, a2);
            a3 = fmaf(bbox_w[3 * CC + c + k], fv, a3);
        }
    }
    out[OUT_LOGITS + b * HWP + p] = ac + cls_b[0];
    out[OUT_BBOX + (b * 4 + 0) * HWP + p] = a0 + bbox_b[0];
    out[OUT_BBOX + (b * 4 + 1) * HWP + p] = a1 + bbox_b[1];
    out[OUT_BBOX + (b * 4 + 2) * HWP + p] = a2 + bbox_b[2];
    out[OUT_BBOX + (b * 4 + 3) * HWP + p] = a3 + bbox_b[3];
}

// ----------------------------------------------------------------------------
extern "C" void kernel_launch(void* const* d_in, const int* in_sizes, int n_in,
                              void* d_out, int out_size, void* d_ws, size_t ws_size,
                              hipStream_t stream)
{
    const float* feature  = (const float*)d_in[0];
    const float* conv_w   = (const float*)d_in[1];
    const float* conv_b   = (const float*)d_in[2];
    const float* loc_w    = (const float*)d_in[3];
    const float* loc_b    = (const float*)d_in[4];
    const float* shape_w  = (const float*)d_in[5];
    const float* shape_b  = (const float*)d_in[6];
    const float* offset_w = (const float*)d_in[7];
    const float* adapt_w  = (const float*)d_in[8];
    const float* cls_w    = (const float*)d_in[9];
    const float* cls_b    = (const float*)d_in[10];
    const float* bbox_w   = (const float*)d_in[11];
    const float* bbox_b   = (const float*)d_in[12];
    float* out = (float*)d_out;

    // workspace partition
    float*          off = (float*)d_ws;                            // 2*72*HWP fp32
    unsigned short* tcf = (unsigned short*)(off + 2 * 72 * HWP);   // NTOT*CC bf16
    unsigned short* fcf = tcf + (size_t)NTOT * CC;                 // NTOT*CC bf16
    unsigned short* tacf = fcf;   // alias: f_cf dead after gemm1
    unsigned short* W1  = fcf + (size_t)NTOT * CC;                 // CC*K1 bf16
    unsigned short* W2  = W1 + (size_t)CC * K1;
    unsigned short* zp  = W2 + (size_t)CC * K1;                    // 1024 zeros
    unsigned short* X2  = zp + 1024;                               // up to NTOT*K1 bf16

    const size_t base_bytes = (size_t)((char*)X2 - (char*)d_ws);
    const bool full = ws_size >= base_bytes + (size_t)NTOT * K1 * 2;  // both-batch X2?

    prep_kernel<<<(CC * K1 + 255) / 256, 256, 0, stream>>>(conv_w, adapt_w, W1, W2, zp);
    transpose_kernel<<<dim3(HWP / 64, BB), 256, 0, stream>>>(feature, fcf);
    gemm1_kernel<<<dim3(NTOT / 64, 2), 256, 0, stream>>>(W1, fcf, conv_b, zp, tcf);
    heads1_kernel<<<dim3(HWP / 256, BB), 256, 0, stream>>>(
        tcf, loc_w, loc_b, shape_w, shape_b, offset_w, out, off);
    if (full) {
        sample_kernel<<<dim3(HWP / 4, BB), 256, 0, stream>>>(tcf, off, X2, 0);
        gemm2_kernel<<<dim3(NTOT / 64, 2), 256, 0, stream>>>(W2, X2, tacf, 0);
    } else {
        for (int b = 0; b < BB; b++) {
            sample_kernel<<<dim3(HWP / 4, 1), 256, 0, stream>>>(tcf, off, X2, b);
            gemm2_kernel<<<dim3(HWP / 64, 2), 256, 0, stream>>>(W2, X2, tacf, b * HWP);
        }
    }
    heads2_kernel<<<dim3(HWP / 256, BB), 256, 0, stream>>>(
        tacf, cls_w, cls_b, bbox_w, bbox_b, out);
}